// Round 10
// baseline (896.704 us; speedup 1.0000x reference)
//
#include <hip/hip_runtime.h>
#include <hip/hip_bf16.h>
#include <cstdint>

typedef short bf16x8 __attribute__((ext_vector_type(8)));
typedef float f32x4 __attribute__((ext_vector_type(4)));
typedef unsigned short u16x8 __attribute__((ext_vector_type(8)));

#define BSHIFT 8
#define NBMAX 512
#define PROP_BLOCKS 2048

__device__ __forceinline__ ushort f2bf(float x) {
  uint32_t u = __float_as_uint(x);
  u += 0x7FFFu + ((u >> 16) & 1u);
  return (ushort)(u >> 16);
}
__device__ __forceinline__ float bf2f(ushort b) {
  return __uint_as_float((uint32_t)b << 16);
}

__device__ __forceinline__ void gload16(const void* g, void* l) {
  __builtin_amdgcn_global_load_lds((const __attribute__((address_space(1))) uint32_t*)g,
                                   (__attribute__((address_space(3))) uint32_t*)l, 16, 0, 0);
}

// ---------------- conversions ----------------
__global__ __launch_bounds__(256) void k_f32_to_bf16(const float* __restrict__ in,
                                                     ushort* __restrict__ out, int n4) {
  int i = blockIdx.x * 256 + threadIdx.x;
  if (i >= n4) return;
  const float4 v = reinterpret_cast<const float4*>(in)[i];
  ushort4 o;
  o.x = f2bf(v.x); o.y = f2bf(v.y); o.z = f2bf(v.z); o.w = f2bf(v.w);
  reinterpret_cast<ushort4*>(out)[i] = o;
}

__global__ __launch_bounds__(256) void k_convT(const float* __restrict__ W,
                                               ushort* __restrict__ Bt, int K, int Nc) {
  int i = blockIdx.x * 256 + threadIdx.x;
  if (i >= K * Nc) return;
  int nn = i / K, kk = i - nn * K;
  Bt[i] = f2bf(W[kk * Nc + nn]);
}

// ---------------- GEMM1: C = relu(A[M,256] @ B[256,128] + bias), bf16, 2-phase dbuf ----------------
__global__ __launch_bounds__(256) void k_gemm1(const ushort* __restrict__ A,
                                               const ushort* __restrict__ Bt,
                                               const float* __restrict__ bias,
                                               ushort* __restrict__ Cout, int M, int ldc) {
  constexpr int BM = 128, BK = 64, KTOT = 256;
  constexpr int WM = 64, WN = 64, MR = 4, NR = 4;  // 2x2 wave grid
  __shared__ ushort lA[2][BM * BK];
  __shared__ ushort lB[2][BM * BK];
  const int tid = threadIdx.x;
  const int w = tid >> 6, lane = tid & 63;
  const int wr = w >> 1, wc = w & 1;
  const int bm = blockIdx.x * BM;
  const int bn = blockIdx.y * BM;
  f32x4 acc[MR][NR] = {};

  auto stage = [&](int buf, int ks) {
    #pragma unroll
    for (int c0 = 0; c0 < 4; ++c0) {
      int c = c0 * 256 + tid;
      int r = c >> 3, ch = c & 7;
      int sch = (ch ^ (r & 7)) << 3;
      gload16(A + (size_t)(bm + r) * KTOT + ks + sch, lA[buf] + c * 8);
      gload16(Bt + (size_t)(bn + r) * KTOT + ks + sch, lB[buf] + c * 8);
    }
  };

  stage(0, 0);
  __syncthreads();
  int cur = 0;
  for (int kst = 0; kst < 4; ++kst) {
    if (kst < 3) stage(cur ^ 1, (kst + 1) * BK);
    #pragma unroll
    for (int kk = 0; kk < 2; ++kk) {
      bf16x8 af[MR], bfr[NR];
      int kc = kk * 4 + (lane >> 4);
      #pragma unroll
      for (int m = 0; m < MR; ++m) {
        int r = wr * WM + m * 16 + (lane & 15);
        af[m] = *reinterpret_cast<const bf16x8*>(lA[cur] + r * BK + (kc ^ (r & 7)) * 8);
      }
      #pragma unroll
      for (int n = 0; n < NR; ++n) {
        int r = wc * WN + n * 16 + (lane & 15);
        bfr[n] = *reinterpret_cast<const bf16x8*>(lB[cur] + r * BK + (kc ^ (r & 7)) * 8);
      }
      #pragma unroll
      for (int m = 0; m < MR; ++m)
        #pragma unroll
        for (int n = 0; n < NR; ++n)
          acc[m][n] = __builtin_amdgcn_mfma_f32_16x16x32_bf16(af[m], bfr[n], acc[m][n], 0, 0, 0);
    }
    __syncthreads();
    cur ^= 1;
  }
  #pragma unroll
  for (int m = 0; m < MR; ++m) {
    #pragma unroll
    for (int n = 0; n < NR; ++n) {
      int col = bn + wc * WN + n * 16 + (lane & 15);
      float bv = bias[col];
      #pragma unroll
      for (int j = 0; j < 4; ++j) {
        int row = bm + wr * WM + m * 16 + (lane >> 4) * 4 + j;
        if (row < M) {
          float v = fmaxf(acc[m][n][j] + bv, 0.f);
          Cout[(size_t)row * ldc + col] = f2bf(v);
        }
      }
    }
  }
}

// ---------------- fused layer2 + layer3 + gated-pool init ----------------
__global__ __launch_bounds__(256) void k_gemm23(const ushort* __restrict__ x1,
                                                const ushort* __restrict__ w2t,
                                                const float* __restrict__ b2,
                                                const ushort* __restrict__ w3t,
                                                const float* __restrict__ b3,
                                                const float* __restrict__ svec,
                                                const float* __restrict__ nrm,
                                                float* __restrict__ xout,
                                                ushort* __restrict__ hs0, int M) {
  constexpr int BM = 64, BK = 64, KTOT = 256;
  constexpr int MR = 4, NR = 4;
  __shared__ char smem[40960];
  ushort* lA = (ushort*)smem;
  ushort* lB = (ushort*)(smem + 8192);
  ushort* lh2 = (ushort*)smem;
  const int tid = threadIdx.x;
  const int wv = tid >> 6, lane = tid & 63;
  const int bm = blockIdx.x * BM;
  f32x4 acc[MR][NR] = {};

  for (int ks = 0; ks < KTOT; ks += BK) {
    #pragma unroll
    for (int c0 = 0; c0 < 2; ++c0) {
      int c = c0 * 256 + tid;
      int r = c >> 3, ch = c & 7;
      gload16(x1 + (size_t)(bm + r) * KTOT + ks + ((ch ^ (r & 7)) << 3), lA + c * 8);
    }
    #pragma unroll
    for (int c0 = 0; c0 < 8; ++c0) {
      int c = c0 * 256 + tid;
      int r = c >> 3, ch = c & 7;
      gload16(w2t + (size_t)r * KTOT + ks + ((ch ^ (r & 7)) << 3), lB + c * 8);
    }
    __syncthreads();
    #pragma unroll
    for (int kk = 0; kk < 2; ++kk) {
      bf16x8 af[MR], bfr[NR];
      int kc = kk * 4 + (lane >> 4);
      #pragma unroll
      for (int m = 0; m < MR; ++m) {
        int r = m * 16 + (lane & 15);
        af[m] = *reinterpret_cast<const bf16x8*>(lA + r * BK + (kc ^ (r & 7)) * 8);
      }
      #pragma unroll
      for (int n = 0; n < NR; ++n) {
        int r = wv * 64 + n * 16 + (lane & 15);
        bfr[n] = *reinterpret_cast<const bf16x8*>(lB + r * BK + (kc ^ (r & 7)) * 8);
      }
      #pragma unroll
      for (int m = 0; m < MR; ++m)
        #pragma unroll
        for (int n = 0; n < NR; ++n)
          acc[m][n] = __builtin_amdgcn_mfma_f32_16x16x32_bf16(af[m], bfr[n], acc[m][n], 0, 0, 0);
    }
    __syncthreads();
  }

  #pragma unroll
  for (int n = 0; n < NR; ++n) {
    int col = wv * 64 + n * 16 + (lane & 15);
    float bv = b2[col];
    #pragma unroll
    for (int m = 0; m < MR; ++m) {
      #pragma unroll
      for (int j = 0; j < 4; ++j) {
        int row = m * 16 + (lane >> 4) * 4 + j;
        float v = fmaxf(acc[m][n][j] + bv, 0.f);
        int ch = col >> 3;
        int within = col & 7;
        lh2[row * 256 + ((ch ^ (row & 7)) << 3) + within] = f2bf(v);
      }
    }
  }
  __syncthreads();

  f32x4 acc3[2] = {};
  #pragma unroll
  for (int ks3 = 0; ks3 < 8; ++ks3) {
    int row = wv * 16 + (lane & 15);
    int kc = ks3 * 4 + (lane >> 4);
    bf16x8 af = *reinterpret_cast<const bf16x8*>(lh2 + row * 256 + ((kc ^ (row & 7)) << 3));
    #pragma unroll
    for (int n = 0; n < 2; ++n) {
      int col = n * 16 + (lane & 15);
      bf16x8 bfr = *reinterpret_cast<const bf16x8*>(w3t + (size_t)col * KTOT + kc * 8);
      acc3[n] = __builtin_amdgcn_mfma_f32_16x16x32_bf16(af, bfr, acc3[n], 0, 0, 0);
    }
  }
  float bb0 = b3[(lane & 15)];
  float bb1 = b3[16 + (lane & 15)];
  float sv0 = svec[(lane & 15)];
  float sv1 = svec[16 + (lane & 15)];
  #pragma unroll
  for (int j = 0; j < 4; ++j) {
    float x0 = acc3[0][j] + bb0;
    float x1v = acc3[1][j] + bb1;
    float p = x0 * sv0 + x1v * sv1;
    #pragma unroll
    for (int msk = 1; msk <= 8; msk <<= 1) p += __shfl_xor(p, msk);
    float g = 1.f / (1.f + __expf(-p));
    int row = bm + wv * 16 + (lane >> 4) * 4 + j;
    if (row < M) {
      float nv = nrm[row];
      xout[(size_t)row * 32 + (lane & 15)] = g * x0;
      xout[(size_t)row * 32 + 16 + (lane & 15)] = g * x1v;
      hs0[(size_t)row * 32 + (lane & 15)] = f2bf(x0 * nv);
      hs0[(size_t)row * 32 + 16 + (lane & 15)] = f2bf(x1v * nv);
    }
  }
}

// ---------------- graph prep ----------------
__global__ __launch_bounds__(256) void k_bucket_hist(const int* __restrict__ dst,
                                                     int* __restrict__ bhist, int E) {
  __shared__ int lh[NBMAX];
  const int t = threadIdx.x;
  const int base = blockIdx.x * 4096;
  for (int i = t; i < NBMAX; i += 256) lh[i] = 0;
  __syncthreads();
  #pragma unroll
  for (int j = 0; j < 16; ++j) {
    int e = base + t + j * 256;
    if (e < E) atomicAdd(&lh[dst[e] >> BSHIFT], 1);
  }
  __syncthreads();
  for (int i = t; i < NBMAX; i += 256)
    if (lh[i]) atomicAdd(&bhist[i], lh[i]);
}

__global__ __launch_bounds__(256) void k_bucket_scan(const int* __restrict__ bhist,
                                                     int* __restrict__ bbase) {
  __shared__ int sh[256];
  int t = threadIdx.x;
  int v0 = bhist[2 * t], v1 = bhist[2 * t + 1];
  int s = v0 + v1;
  sh[t] = s;
  __syncthreads();
  for (int off = 1; off < 256; off <<= 1) {
    int x = (t >= off) ? sh[t - off] : 0;
    __syncthreads();
    sh[t] += x;
    __syncthreads();
  }
  int pre = sh[t] - s;
  bbase[2 * t] = pre;
  bbase[2 * t + 1] = pre + v0;
  if (t == 255) bbase[NBMAX] = sh[255];
}

__global__ __launch_bounds__(256) void k_bucket_scatter(const int* __restrict__ src,
                                                        const int* __restrict__ dst,
                                                        const int* __restrict__ bbase,
                                                        int* __restrict__ gfill,
                                                        int* __restrict__ tmp,
                                                        int E, int nbuck) {
  __shared__ int lhist[NBMAX];
  __shared__ int lbase[NBMAX];
  const int t = threadIdx.x;
  const int base = blockIdx.x * 4096;
  for (int i = t; i < NBMAX; i += 256) lhist[i] = 0;
  __syncthreads();
  int myd[16];
  #pragma unroll
  for (int j = 0; j < 16; ++j) {
    int e = base + t + j * 256;
    myd[j] = (e < E) ? dst[e] : -1;
    if (myd[j] >= 0) atomicAdd(&lhist[myd[j] >> BSHIFT], 1);
  }
  __syncthreads();
  for (int i = t; i < nbuck; i += 256) {
    int c = lhist[i];
    lbase[i] = (c > 0) ? atomicAdd(&gfill[i], c) : 0;
    lhist[i] = 0;
  }
  __syncthreads();
  #pragma unroll
  for (int j = 0; j < 16; ++j) {
    int e = base + t + j * 256;
    if (myd[j] >= 0) {
      int b = myd[j] >> BSHIFT;
      int r = atomicAdd(&lhist[b], 1);
      int pos = bbase[b] + lbase[b] + r;
      tmp[pos] = src[e] | ((myd[j] & 255) << 17);
    }
  }
}

__global__ __launch_bounds__(256) void k_bucket_sort(const int* __restrict__ tmp,
                                                     const int* __restrict__ bbase,
                                                     int* __restrict__ rp,
                                                     float* __restrict__ nrm,
                                                     float* __restrict__ invdeg,
                                                     float* __restrict__ sdeg,
                                                     int* __restrict__ ss,
                                                     int Nn, int E) {
  __shared__ int lcnt[256];
  __shared__ int sh[256];
  __shared__ int lpre[256];
  __shared__ int lfill[256];
  const int t = threadIdx.x;
  const int b = blockIdx.x;
  const int node0 = b << BSHIFT;
  const int seg0 = bbase[b], seg1 = bbase[b + 1];
  lcnt[t] = 0;
  lfill[t] = 0;
  __syncthreads();
  for (int i = seg0 + t; i < seg1; i += 256)
    atomicAdd(&lcnt[tmp[i] >> 17], 1);
  __syncthreads();
  int c = lcnt[t];
  sh[t] = c;
  __syncthreads();
  for (int off = 1; off < 256; off <<= 1) {
    int x = (t >= off) ? sh[t - off] : 0;
    __syncthreads();
    sh[t] += x;
    __syncthreads();
  }
  int pre = seg0 + sh[t] - c;
  lpre[t] = pre;
  int node = node0 + t;
  if (node < Nn) {
    rp[node] = pre;
    nrm[node] = (c > 0) ? rsqrtf((float)c) : 0.f;
    invdeg[node] = (c > 0) ? (1.f / (float)c) : 0.f;
    sdeg[node] = sqrtf((float)c);
  }
  if (b == 0 && t == 0) rp[Nn] = E;
  __syncthreads();
  for (int i = seg0 + t; i < seg1; i += 256) {
    int p = tmp[i];
    int n = p >> 17;
    int r = atomicAdd(&lfill[n], 1);
    ss[lpre[n] + r] = p & 0x1FFFF;
  }
}

// ---------------- one propagation hop: hs_out = (sum_{src} hs_in[src]) * invdeg ----------------
// Grid-stride: fixed 2048 blocks (8192 waves = 32 waves/CU), each wave owns ~12 nodes.
// Per node: 2-deep clamped preload (32 rows in flight); tail loop for deg>32.
__global__ __launch_bounds__(256) void k_prop(const ushort* __restrict__ hs_in,
                                              ushort* __restrict__ hs_out,
                                              const int* __restrict__ rp,
                                              const int* __restrict__ ss,
                                              const float* __restrict__ invdeg, int Nn) {
  const int wave = threadIdx.x >> 6;
  const int lane = threadIdx.x & 63;
  const int e16 = lane >> 2;
  const int d4 = lane & 3;
  const int gw = blockIdx.x * 4 + wave;
  const int nw = gridDim.x * 4;
  for (int v = gw; v < Nn; v += nw) {
    const int beg = rp[v], end = rp[v + 1];
    float a0 = 0, a1 = 0, a2 = 0, a3 = 0, a4 = 0, a5 = 0, a6 = 0, a7 = 0;
    if (beg < end) {
      const int i0 = beg + e16;
      const int i1 = i0 + 16;
      const int last = end - 1;
      const int u0 = ss[min(i0, last)];
      const int u1 = ss[min(i1, last)];
      const u16x8 h0 = *reinterpret_cast<const u16x8*>(hs_in + (size_t)u0 * 32 + d4 * 8);
      const u16x8 h1 = *reinterpret_cast<const u16x8*>(hs_in + (size_t)u1 * 32 + d4 * 8);
      const float m0 = (i0 < end) ? 1.f : 0.f;
      const float m1 = (i1 < end) ? 1.f : 0.f;
      a0 = fmaf(m0, bf2f(h0[0]), m1 * bf2f(h1[0]));
      a1 = fmaf(m0, bf2f(h0[1]), m1 * bf2f(h1[1]));
      a2 = fmaf(m0, bf2f(h0[2]), m1 * bf2f(h1[2]));
      a3 = fmaf(m0, bf2f(h0[3]), m1 * bf2f(h1[3]));
      a4 = fmaf(m0, bf2f(h0[4]), m1 * bf2f(h1[4]));
      a5 = fmaf(m0, bf2f(h0[5]), m1 * bf2f(h1[5]));
      a6 = fmaf(m0, bf2f(h0[6]), m1 * bf2f(h1[6]));
      a7 = fmaf(m0, bf2f(h0[7]), m1 * bf2f(h1[7]));
      for (int i = i1 + 16; i < end; i += 16) {
        int u = ss[i];
        u16x8 h = *reinterpret_cast<const u16x8*>(hs_in + (size_t)u * 32 + d4 * 8);
        a0 += bf2f(h[0]); a1 += bf2f(h[1]); a2 += bf2f(h[2]); a3 += bf2f(h[3]);
        a4 += bf2f(h[4]); a5 += bf2f(h[5]); a6 += bf2f(h[6]); a7 += bf2f(h[7]);
      }
    }
    #pragma unroll
    for (int m = 4; m <= 32; m <<= 1) {
      a0 += __shfl_xor(a0, m); a1 += __shfl_xor(a1, m);
      a2 += __shfl_xor(a2, m); a3 += __shfl_xor(a3, m);
      a4 += __shfl_xor(a4, m); a5 += __shfl_xor(a5, m);
      a6 += __shfl_xor(a6, m); a7 += __shfl_xor(a7, m);
    }
    if (e16 == 0) {
      const float idv = invdeg[v];
      u16x8 hn;
      hn[0] = f2bf(a0 * idv); hn[1] = f2bf(a1 * idv); hn[2] = f2bf(a2 * idv); hn[3] = f2bf(a3 * idv);
      hn[4] = f2bf(a4 * idv); hn[5] = f2bf(a5 * idv); hn[6] = f2bf(a6 * idv); hn[7] = f2bf(a7 * idv);
      *reinterpret_cast<u16x8*>(hs_out + (size_t)v * 32 + d4 * 8) = hn;
    }
  }
}

// ---------------- final pooling: xout[v] += sum_{k=1..16} sigmoid(H_k . s) * H_k ----------------
__global__ __launch_bounds__(256) void k_pool(const ushort* __restrict__ hsF,   // hops 0..7
                                              const ushort* __restrict__ hsX,   // hops 8..15
                                              const ushort* __restrict__ hs16,
                                              const float* __restrict__ sdeg,
                                              const float* __restrict__ svec,
                                              float* __restrict__ xout, int Nn) {
  const int t = blockIdx.x * 256 + threadIdx.x;
  const int v = t >> 2;
  const int d4 = t & 3;
  if (v >= Nn) return;
  const float sd = sdeg[v];
  const float4 svA = *reinterpret_cast<const float4*>(svec + d4 * 8);
  const float4 svB = *reinterpret_cast<const float4*>(svec + d4 * 8 + 4);
  const size_t seg = (size_t)Nn * 32;
  const size_t off = (size_t)v * 32 + d4 * 8;
  float o0 = 0, o1 = 0, o2 = 0, o3 = 0, o4 = 0, o5 = 0, o6 = 0, o7 = 0;
  #pragma unroll
  for (int k = 1; k <= 16; ++k) {
    const ushort* hp = (k < 8) ? (hsF + (size_t)k * seg)
                     : (k < 16) ? (hsX + (size_t)(k - 8) * seg)
                                : hs16;
    u16x8 h = *reinterpret_cast<const u16x8*>(hp + off);
    float h0 = bf2f(h[0]) * sd, h1 = bf2f(h[1]) * sd, h2 = bf2f(h[2]) * sd, h3 = bf2f(h[3]) * sd;
    float h4 = bf2f(h[4]) * sd, h5 = bf2f(h[5]) * sd, h6 = bf2f(h[6]) * sd, h7 = bf2f(h[7]) * sd;
    float p = h0 * svA.x + h1 * svA.y + h2 * svA.z + h3 * svA.w
            + h4 * svB.x + h5 * svB.y + h6 * svB.z + h7 * svB.w;
    p += __shfl_xor(p, 1);
    p += __shfl_xor(p, 2);
    const float g = 1.f / (1.f + __expf(-p));
    o0 += g * h0; o1 += g * h1; o2 += g * h2; o3 += g * h3;
    o4 += g * h4; o5 += g * h5; o6 += g * h6; o7 += g * h7;
  }
  float4* oa = reinterpret_cast<float4*>(xout + off);
  float4 q0 = oa[0], q1 = oa[1];
  q0.x += o0; q0.y += o1; q0.z += o2; q0.w += o3;
  q1.x += o4; q1.y += o5; q1.z += o6; q1.w += o7;
  oa[0] = q0; oa[1] = q1;
}

// ---------------- launch ----------------
extern "C" void kernel_launch(void* const* d_in, const int* in_sizes, int n_in,
                              void* d_out, int out_size, void* d_ws, size_t ws_size,
                              hipStream_t stream) {
  const float* feats = (const float*)d_in[0];
  const float* W1 = (const float*)d_in[1];
  const float* b1 = (const float*)d_in[2];
  const float* W2 = (const float*)d_in[3];
  const float* b2 = (const float*)d_in[4];
  const float* W3 = (const float*)d_in[5];
  const float* b3 = (const float*)d_in[6];
  const float* svec = (const float*)d_in[7];
  const int* src = (const int*)d_in[8];
  const int* dst = (const int*)d_in[9];

  const int DIN = 256, DH = 256, DOUT = 32, KHOP = 16;
  const int N = in_sizes[0] / DIN;
  const int E = in_sizes[8];
  const int nbuck = (N + (1 << BSHIFT) - 1) >> BSHIFT;

  char* w = (char*)d_ws;
  auto alloc = [&](size_t bytes) {
    char* p = w;
    w += (bytes + 255) & ~(size_t)255;
    return p;
  };
  ushort* featsb = (ushort*)alloc((size_t)N * DIN * 2);  // after gemm1: hs buffers 0..7
  ushort* x1b = (ushort*)alloc((size_t)N * DH * 2);      // after gemm23: hs buffers 8..15
  ushort* w1t = (ushort*)alloc((size_t)DIN * DH * 2);
  ushort* w2t = (ushort*)alloc((size_t)DH * DH * 2);
  ushort* w3t = (ushort*)alloc((size_t)DH * DOUT * 2);
  ushort* hs16 = (ushort*)alloc((size_t)N * DOUT * 2);
  float* nrm = (float*)alloc((size_t)N * 4);
  float* invdeg = (float*)alloc((size_t)N * 4);
  float* sdeg = (float*)alloc((size_t)N * 4);
  int* rp  = (int*)alloc((size_t)(N + 1) * 4);
  int* bhist = (int*)alloc((size_t)NBMAX * 4);
  int* bbase = (int*)alloc((size_t)(NBMAX + 1) * 4);
  int* gfill = (int*)alloc((size_t)NBMAX * 4);
  int* ss  = (int*)alloc((size_t)E * 4);
  int* tmp = (int*)alloc((size_t)E * 4);
  float* xout = (float*)d_out;

  const size_t seg = (size_t)N * DOUT;  // ushorts per hop buffer
  auto hsptr = [&](int k) -> ushort* {
    if (k < 8) return featsb + (size_t)k * seg;
    if (k < 16) return x1b + (size_t)(k - 8) * seg;
    return hs16;
  };

  // conversions
  k_f32_to_bf16<<<dim3((N * DIN / 4 + 255) / 256), 256, 0, stream>>>(feats, featsb, N * DIN / 4);
  k_convT<<<dim3((DIN * DH + 255) / 256), 256, 0, stream>>>(W1, w1t, DIN, DH);
  k_convT<<<dim3((DH * DH + 255) / 256), 256, 0, stream>>>(W2, w2t, DH, DH);
  k_convT<<<dim3((DH * DOUT + 255) / 256), 256, 0, stream>>>(W3, w3t, DH, DOUT);

  // graph prep
  (void)hipMemsetAsync(bhist, 0, (size_t)NBMAX * 4, stream);
  (void)hipMemsetAsync(gfill, 0, (size_t)NBMAX * 4, stream);
  int nchunk = (E + 4095) / 4096;
  k_bucket_hist<<<dim3(nchunk), 256, 0, stream>>>(dst, bhist, E);
  k_bucket_scan<<<dim3(1), 256, 0, stream>>>(bhist, bbase);
  k_bucket_scatter<<<dim3(nchunk), 256, 0, stream>>>(src, dst, bbase, gfill, tmp, E, nbuck);
  k_bucket_sort<<<dim3(nbuck), 256, 0, stream>>>(tmp, bbase, rp, nrm, invdeg, sdeg, ss, N, E);

  // MLP: GEMM1 then fused GEMM2+GEMM3+hop0-pool
  dim3 g1((N + 127) / 128, DH / 128);
  k_gemm1<<<g1, 256, 0, stream>>>(featsb, w1t, b1, x1b, N, DH);
  k_gemm23<<<dim3((N + 63) / 64), 256, 0, stream>>>(x1b, w2t, b2, w3t, b3, svec, nrm, xout,
                                                    hsptr(0), N);

  // 16 hops (grid-stride, fixed 2048 blocks), then one pooling pass over hops 1..16
  for (int h = 0; h < KHOP; ++h) {
    k_prop<<<dim3(PROP_BLOCKS), 256, 0, stream>>>(hsptr(h), hsptr(h + 1), rp, ss, invdeg, N);
  }
  k_pool<<<dim3((N * 4 + 255) / 256), 256, 0, stream>>>(hsptr(0), hsptr(8), hs16, sdeg, svec,
                                                        xout, N);
}

// Round 11
// 745.296 us; speedup vs baseline: 1.2032x; 1.2032x over previous
//
#include <hip/hip_runtime.h>
#include <hip/hip_bf16.h>
#include <cstdint>

typedef short bf16x8 __attribute__((ext_vector_type(8)));
typedef float f32x4 __attribute__((ext_vector_type(4)));
typedef unsigned short u16x8 __attribute__((ext_vector_type(8)));

#define BSHIFT 8
#define NBMAX 512

__device__ __forceinline__ ushort f2bf(float x) {
  uint32_t u = __float_as_uint(x);
  u += 0x7FFFu + ((u >> 16) & 1u);
  return (ushort)(u >> 16);
}
__device__ __forceinline__ float bf2f(ushort b) {
  return __uint_as_float((uint32_t)b << 16);
}

__device__ __forceinline__ void gload16(const void* g, void* l) {
  __builtin_amdgcn_global_load_lds((const __attribute__((address_space(1))) uint32_t*)g,
                                   (__attribute__((address_space(3))) uint32_t*)l, 16, 0, 0);
}

// ---------------- conversions ----------------
__global__ __launch_bounds__(256) void k_f32_to_bf16(const float* __restrict__ in,
                                                     ushort* __restrict__ out, int n4) {
  int i = blockIdx.x * 256 + threadIdx.x;
  if (i >= n4) return;
  const float4 v = reinterpret_cast<const float4*>(in)[i];
  ushort4 o;
  o.x = f2bf(v.x); o.y = f2bf(v.y); o.z = f2bf(v.z); o.w = f2bf(v.w);
  reinterpret_cast<ushort4*>(out)[i] = o;
}

__global__ __launch_bounds__(256) void k_convT(const float* __restrict__ W,
                                               ushort* __restrict__ Bt, int K, int Nc) {
  int i = blockIdx.x * 256 + threadIdx.x;
  if (i >= K * Nc) return;
  int nn = i / K, kk = i - nn * K;
  Bt[i] = f2bf(W[kk * Nc + nn]);
}

// ---------------- GEMM1: C = relu(A[M,256] @ B[256,128] + bias), bf16, 2-phase dbuf ----------------
__global__ __launch_bounds__(256) void k_gemm1(const ushort* __restrict__ A,
                                               const ushort* __restrict__ Bt,
                                               const float* __restrict__ bias,
                                               ushort* __restrict__ Cout, int M, int ldc) {
  constexpr int BM = 128, BK = 64, KTOT = 256;
  constexpr int WM = 64, WN = 64, MR = 4, NR = 4;  // 2x2 wave grid
  __shared__ ushort lA[2][BM * BK];
  __shared__ ushort lB[2][BM * BK];
  const int tid = threadIdx.x;
  const int w = tid >> 6, lane = tid & 63;
  const int wr = w >> 1, wc = w & 1;
  const int bm = blockIdx.x * BM;
  const int bn = blockIdx.y * BM;
  f32x4 acc[MR][NR] = {};

  auto stage = [&](int buf, int ks) {
    #pragma unroll
    for (int c0 = 0; c0 < 4; ++c0) {
      int c = c0 * 256 + tid;
      int r = c >> 3, ch = c & 7;
      int sch = (ch ^ (r & 7)) << 3;
      gload16(A + (size_t)(bm + r) * KTOT + ks + sch, lA[buf] + c * 8);
      gload16(Bt + (size_t)(bn + r) * KTOT + ks + sch, lB[buf] + c * 8);
    }
  };

  stage(0, 0);
  __syncthreads();
  int cur = 0;
  for (int kst = 0; kst < 4; ++kst) {
    if (kst < 3) stage(cur ^ 1, (kst + 1) * BK);
    #pragma unroll
    for (int kk = 0; kk < 2; ++kk) {
      bf16x8 af[MR], bfr[NR];
      int kc = kk * 4 + (lane >> 4);
      #pragma unroll
      for (int m = 0; m < MR; ++m) {
        int r = wr * WM + m * 16 + (lane & 15);
        af[m] = *reinterpret_cast<const bf16x8*>(lA[cur] + r * BK + (kc ^ (r & 7)) * 8);
      }
      #pragma unroll
      for (int n = 0; n < NR; ++n) {
        int r = wc * WN + n * 16 + (lane & 15);
        bfr[n] = *reinterpret_cast<const bf16x8*>(lB[cur] + r * BK + (kc ^ (r & 7)) * 8);
      }
      #pragma unroll
      for (int m = 0; m < MR; ++m)
        #pragma unroll
        for (int n = 0; n < NR; ++n)
          acc[m][n] = __builtin_amdgcn_mfma_f32_16x16x32_bf16(af[m], bfr[n], acc[m][n], 0, 0, 0);
    }
    __syncthreads();
    cur ^= 1;
  }
  #pragma unroll
  for (int m = 0; m < MR; ++m) {
    #pragma unroll
    for (int n = 0; n < NR; ++n) {
      int col = bn + wc * WN + n * 16 + (lane & 15);
      float bv = bias[col];
      #pragma unroll
      for (int j = 0; j < 4; ++j) {
        int row = bm + wr * WM + m * 16 + (lane >> 4) * 4 + j;
        if (row < M) {
          float v = fmaxf(acc[m][n][j] + bv, 0.f);
          Cout[(size_t)row * ldc + col] = f2bf(v);
        }
      }
    }
  }
}

// ---------------- fused layer2 + layer3 + gated-pool init ----------------
__global__ __launch_bounds__(256) void k_gemm23(const ushort* __restrict__ x1,
                                                const ushort* __restrict__ w2t,
                                                const float* __restrict__ b2,
                                                const ushort* __restrict__ w3t,
                                                const float* __restrict__ b3,
                                                const float* __restrict__ svec,
                                                const float* __restrict__ nrm,
                                                float* __restrict__ xout,
                                                ushort* __restrict__ hs0, int M) {
  constexpr int BM = 64, BK = 64, KTOT = 256;
  constexpr int MR = 4, NR = 4;
  __shared__ char smem[40960];
  ushort* lA = (ushort*)smem;
  ushort* lB = (ushort*)(smem + 8192);
  ushort* lh2 = (ushort*)smem;
  const int tid = threadIdx.x;
  const int wv = tid >> 6, lane = tid & 63;
  const int bm = blockIdx.x * BM;
  f32x4 acc[MR][NR] = {};

  for (int ks = 0; ks < KTOT; ks += BK) {
    #pragma unroll
    for (int c0 = 0; c0 < 2; ++c0) {
      int c = c0 * 256 + tid;
      int r = c >> 3, ch = c & 7;
      gload16(x1 + (size_t)(bm + r) * KTOT + ks + ((ch ^ (r & 7)) << 3), lA + c * 8);
    }
    #pragma unroll
    for (int c0 = 0; c0 < 8; ++c0) {
      int c = c0 * 256 + tid;
      int r = c >> 3, ch = c & 7;
      gload16(w2t + (size_t)r * KTOT + ks + ((ch ^ (r & 7)) << 3), lB + c * 8);
    }
    __syncthreads();
    #pragma unroll
    for (int kk = 0; kk < 2; ++kk) {
      bf16x8 af[MR], bfr[NR];
      int kc = kk * 4 + (lane >> 4);
      #pragma unroll
      for (int m = 0; m < MR; ++m) {
        int r = m * 16 + (lane & 15);
        af[m] = *reinterpret_cast<const bf16x8*>(lA + r * BK + (kc ^ (r & 7)) * 8);
      }
      #pragma unroll
      for (int n = 0; n < NR; ++n) {
        int r = wv * 64 + n * 16 + (lane & 15);
        bfr[n] = *reinterpret_cast<const bf16x8*>(lB + r * BK + (kc ^ (r & 7)) * 8);
      }
      #pragma unroll
      for (int m = 0; m < MR; ++m)
        #pragma unroll
        for (int n = 0; n < NR; ++n)
          acc[m][n] = __builtin_amdgcn_mfma_f32_16x16x32_bf16(af[m], bfr[n], acc[m][n], 0, 0, 0);
    }
    __syncthreads();
  }

  #pragma unroll
  for (int n = 0; n < NR; ++n) {
    int col = wv * 64 + n * 16 + (lane & 15);
    float bv = b2[col];
    #pragma unroll
    for (int m = 0; m < MR; ++m) {
      #pragma unroll
      for (int j = 0; j < 4; ++j) {
        int row = m * 16 + (lane >> 4) * 4 + j;
        float v = fmaxf(acc[m][n][j] + bv, 0.f);
        int ch = col >> 3;
        int within = col & 7;
        lh2[row * 256 + ((ch ^ (row & 7)) << 3) + within] = f2bf(v);
      }
    }
  }
  __syncthreads();

  f32x4 acc3[2] = {};
  #pragma unroll
  for (int ks3 = 0; ks3 < 8; ++ks3) {
    int row = wv * 16 + (lane & 15);
    int kc = ks3 * 4 + (lane >> 4);
    bf16x8 af = *reinterpret_cast<const bf16x8*>(lh2 + row * 256 + ((kc ^ (row & 7)) << 3));
    #pragma unroll
    for (int n = 0; n < 2; ++n) {
      int col = n * 16 + (lane & 15);
      bf16x8 bfr = *reinterpret_cast<const bf16x8*>(w3t + (size_t)col * KTOT + kc * 8);
      acc3[n] = __builtin_amdgcn_mfma_f32_16x16x32_bf16(af, bfr, acc3[n], 0, 0, 0);
    }
  }
  float bb0 = b3[(lane & 15)];
  float bb1 = b3[16 + (lane & 15)];
  float sv0 = svec[(lane & 15)];
  float sv1 = svec[16 + (lane & 15)];
  #pragma unroll
  for (int j = 0; j < 4; ++j) {
    float x0 = acc3[0][j] + bb0;
    float x1v = acc3[1][j] + bb1;
    float p = x0 * sv0 + x1v * sv1;
    #pragma unroll
    for (int msk = 1; msk <= 8; msk <<= 1) p += __shfl_xor(p, msk);
    float g = 1.f / (1.f + __expf(-p));
    int row = bm + wv * 16 + (lane >> 4) * 4 + j;
    if (row < M) {
      float nv = nrm[row];
      xout[(size_t)row * 32 + (lane & 15)] = g * x0;
      xout[(size_t)row * 32 + 16 + (lane & 15)] = g * x1v;
      hs0[(size_t)row * 32 + (lane & 15)] = f2bf(x0 * nv);
      hs0[(size_t)row * 32 + 16 + (lane & 15)] = f2bf(x1v * nv);
    }
  }
}

// ---------------- graph prep ----------------
__global__ __launch_bounds__(256) void k_bucket_hist(const int* __restrict__ dst,
                                                     int* __restrict__ bhist, int E) {
  __shared__ int lh[NBMAX];
  const int t = threadIdx.x;
  const int base = blockIdx.x * 4096;
  for (int i = t; i < NBMAX; i += 256) lh[i] = 0;
  __syncthreads();
  #pragma unroll
  for (int j = 0; j < 16; ++j) {
    int e = base + t + j * 256;
    if (e < E) atomicAdd(&lh[dst[e] >> BSHIFT], 1);
  }
  __syncthreads();
  for (int i = t; i < NBMAX; i += 256)
    if (lh[i]) atomicAdd(&bhist[i], lh[i]);
}

__global__ __launch_bounds__(256) void k_bucket_scan(const int* __restrict__ bhist,
                                                     int* __restrict__ bbase) {
  __shared__ int sh[256];
  int t = threadIdx.x;
  int v0 = bhist[2 * t], v1 = bhist[2 * t + 1];
  int s = v0 + v1;
  sh[t] = s;
  __syncthreads();
  for (int off = 1; off < 256; off <<= 1) {
    int x = (t >= off) ? sh[t - off] : 0;
    __syncthreads();
    sh[t] += x;
    __syncthreads();
  }
  int pre = sh[t] - s;
  bbase[2 * t] = pre;
  bbase[2 * t + 1] = pre + v0;
  if (t == 255) bbase[NBMAX] = sh[255];
}

__global__ __launch_bounds__(256) void k_bucket_scatter(const int* __restrict__ src,
                                                        const int* __restrict__ dst,
                                                        const int* __restrict__ bbase,
                                                        int* __restrict__ gfill,
                                                        int* __restrict__ tmp,
                                                        int E, int nbuck) {
  __shared__ int lhist[NBMAX];
  __shared__ int lbase[NBMAX];
  const int t = threadIdx.x;
  const int base = blockIdx.x * 4096;
  for (int i = t; i < NBMAX; i += 256) lhist[i] = 0;
  __syncthreads();
  int myd[16];
  #pragma unroll
  for (int j = 0; j < 16; ++j) {
    int e = base + t + j * 256;
    myd[j] = (e < E) ? dst[e] : -1;
    if (myd[j] >= 0) atomicAdd(&lhist[myd[j] >> BSHIFT], 1);
  }
  __syncthreads();
  for (int i = t; i < nbuck; i += 256) {
    int c = lhist[i];
    lbase[i] = (c > 0) ? atomicAdd(&gfill[i], c) : 0;
    lhist[i] = 0;
  }
  __syncthreads();
  #pragma unroll
  for (int j = 0; j < 16; ++j) {
    int e = base + t + j * 256;
    if (myd[j] >= 0) {
      int b = myd[j] >> BSHIFT;
      int r = atomicAdd(&lhist[b], 1);
      int pos = bbase[b] + lbase[b] + r;
      tmp[pos] = src[e] | ((myd[j] & 255) << 17);
    }
  }
}

__global__ __launch_bounds__(256) void k_bucket_sort(const int* __restrict__ tmp,
                                                     const int* __restrict__ bbase,
                                                     int* __restrict__ rp,
                                                     float* __restrict__ nrm,
                                                     float* __restrict__ invdeg,
                                                     float* __restrict__ sdeg,
                                                     int* __restrict__ ss,
                                                     int Nn, int E) {
  __shared__ int lcnt[256];
  __shared__ int sh[256];
  __shared__ int lpre[256];
  __shared__ int lfill[256];
  const int t = threadIdx.x;
  const int b = blockIdx.x;
  const int node0 = b << BSHIFT;
  const int seg0 = bbase[b], seg1 = bbase[b + 1];
  lcnt[t] = 0;
  lfill[t] = 0;
  __syncthreads();
  for (int i = seg0 + t; i < seg1; i += 256)
    atomicAdd(&lcnt[tmp[i] >> 17], 1);
  __syncthreads();
  int c = lcnt[t];
  sh[t] = c;
  __syncthreads();
  for (int off = 1; off < 256; off <<= 1) {
    int x = (t >= off) ? sh[t - off] : 0;
    __syncthreads();
    sh[t] += x;
    __syncthreads();
  }
  int pre = seg0 + sh[t] - c;
  lpre[t] = pre;
  int node = node0 + t;
  if (node < Nn) {
    rp[node] = pre;
    nrm[node] = (c > 0) ? rsqrtf((float)c) : 0.f;
    invdeg[node] = (c > 0) ? (1.f / (float)c) : 0.f;
    sdeg[node] = sqrtf((float)c);
  }
  if (b == 0 && t == 0) rp[Nn] = E;
  __syncthreads();
  for (int i = seg0 + t; i < seg1; i += 256) {
    int p = tmp[i];
    int n = p >> 17;
    int r = atomicAdd(&lfill[n], 1);
    ss[lpre[n] + r] = p & 0x1FFFF;
  }
}

// ---------------- one propagation hop: hs_out = (sum_{src} hs_in[src]) * invdeg ----------------
// One node per wave; lane = e4*16 + d16: 4 edge slots x 16 lanes x 4B (2 bf16 dims).
// 16 edges covered by 4 independent (ss,row) load pairs -> 16 rows in flight,
// and the edge reduce is only 2 shuffle levels x 2 values (vs 4 levels x 8).
__global__ __launch_bounds__(256) void k_prop(const ushort* __restrict__ hs_in,
                                              ushort* __restrict__ hs_out,
                                              const int* __restrict__ rp,
                                              const int* __restrict__ ss,
                                              const float* __restrict__ invdeg, int Nn) {
  const int wave = threadIdx.x >> 6;
  const int lane = threadIdx.x & 63;
  const int e4 = lane >> 4;    // edge slot 0..3
  const int d16 = lane & 15;   // dim-pair index (2 bf16 = 4B per lane)
  const int v = blockIdx.x * 4 + wave;
  if (v >= Nn) return;
  const int beg = rp[v], end = rp[v + 1];
  float a0 = 0.f, a1 = 0.f;
  if (beg < end) {
    const int last = end - 1;
    const int i0 = beg + e4, i1 = i0 + 4, i2 = i0 + 8, i3 = i0 + 12;
    const int u0 = ss[min(i0, last)];
    const int u1 = ss[min(i1, last)];
    const int u2 = ss[min(i2, last)];
    const int u3 = ss[min(i3, last)];
    const uint r0 = *reinterpret_cast<const uint*>(hs_in + (size_t)u0 * 32 + d16 * 2);
    const uint r1 = *reinterpret_cast<const uint*>(hs_in + (size_t)u1 * 32 + d16 * 2);
    const uint r2 = *reinterpret_cast<const uint*>(hs_in + (size_t)u2 * 32 + d16 * 2);
    const uint r3 = *reinterpret_cast<const uint*>(hs_in + (size_t)u3 * 32 + d16 * 2);
    const float m0 = (i0 < end) ? 1.f : 0.f;
    const float m1 = (i1 < end) ? 1.f : 0.f;
    const float m2 = (i2 < end) ? 1.f : 0.f;
    const float m3 = (i3 < end) ? 1.f : 0.f;
    a0 = m0 * bf2f((ushort)r0) + m1 * bf2f((ushort)r1)
       + m2 * bf2f((ushort)r2) + m3 * bf2f((ushort)r3);
    a1 = m0 * bf2f((ushort)(r0 >> 16)) + m1 * bf2f((ushort)(r1 >> 16))
       + m2 * bf2f((ushort)(r2 >> 16)) + m3 * bf2f((ushort)(r3 >> 16));
    for (int i = i0 + 16; i < end; i += 4) {   // rare tail (deg > 16)
      int u = ss[i];
      uint r = *reinterpret_cast<const uint*>(hs_in + (size_t)u * 32 + d16 * 2);
      a0 += bf2f((ushort)r);
      a1 += bf2f((ushort)(r >> 16));
    }
  }
  // reduce across the 4 edge slots (lane bits 4,5)
  a0 += __shfl_xor(a0, 16); a1 += __shfl_xor(a1, 16);
  a0 += __shfl_xor(a0, 32); a1 += __shfl_xor(a1, 32);
  if (e4 == 0) {
    const float idv = invdeg[v];
    uint o = (uint)f2bf(a0 * idv) | ((uint)f2bf(a1 * idv) << 16);
    *reinterpret_cast<uint*>(hs_out + (size_t)v * 32 + d16 * 2) = o;
  }
}

// ---------------- final pooling: xout[v] += sum_{k=1..16} sigmoid(H_k . s) * H_k ----------------
__global__ __launch_bounds__(256) void k_pool(const ushort* __restrict__ hsF,   // hops 0..7
                                              const ushort* __restrict__ hsX,   // hops 8..15
                                              const ushort* __restrict__ hs16,
                                              const float* __restrict__ sdeg,
                                              const float* __restrict__ svec,
                                              float* __restrict__ xout, int Nn) {
  const int t = blockIdx.x * 256 + threadIdx.x;
  const int v = t >> 2;
  const int d4 = t & 3;
  if (v >= Nn) return;
  const float sd = sdeg[v];
  const float4 svA = *reinterpret_cast<const float4*>(svec + d4 * 8);
  const float4 svB = *reinterpret_cast<const float4*>(svec + d4 * 8 + 4);
  const size_t seg = (size_t)Nn * 32;
  const size_t off = (size_t)v * 32 + d4 * 8;
  float o0 = 0, o1 = 0, o2 = 0, o3 = 0, o4 = 0, o5 = 0, o6 = 0, o7 = 0;
  #pragma unroll
  for (int k = 1; k <= 16; ++k) {
    const ushort* hp = (k < 8) ? (hsF + (size_t)k * seg)
                     : (k < 16) ? (hsX + (size_t)(k - 8) * seg)
                                : hs16;
    u16x8 h = *reinterpret_cast<const u16x8*>(hp + off);
    float h0 = bf2f(h[0]) * sd, h1 = bf2f(h[1]) * sd, h2 = bf2f(h[2]) * sd, h3 = bf2f(h[3]) * sd;
    float h4 = bf2f(h[4]) * sd, h5 = bf2f(h[5]) * sd, h6 = bf2f(h[6]) * sd, h7 = bf2f(h[7]) * sd;
    float p = h0 * svA.x + h1 * svA.y + h2 * svA.z + h3 * svA.w
            + h4 * svB.x + h5 * svB.y + h6 * svB.z + h7 * svB.w;
    p += __shfl_xor(p, 1);
    p += __shfl_xor(p, 2);
    const float g = 1.f / (1.f + __expf(-p));
    o0 += g * h0; o1 += g * h1; o2 += g * h2; o3 += g * h3;
    o4 += g * h4; o5 += g * h5; o6 += g * h6; o7 += g * h7;
  }
  float4* oa = reinterpret_cast<float4*>(xout + off);
  float4 q0 = oa[0], q1 = oa[1];
  q0.x += o0; q0.y += o1; q0.z += o2; q0.w += o3;
  q1.x += o4; q1.y += o5; q1.z += o6; q1.w += o7;
  oa[0] = q0; oa[1] = q1;
}

// ---------------- launch ----------------
extern "C" void kernel_launch(void* const* d_in, const int* in_sizes, int n_in,
                              void* d_out, int out_size, void* d_ws, size_t ws_size,
                              hipStream_t stream) {
  const float* feats = (const float*)d_in[0];
  const float* W1 = (const float*)d_in[1];
  const float* b1 = (const float*)d_in[2];
  const float* W2 = (const float*)d_in[3];
  const float* b2 = (const float*)d_in[4];
  const float* W3 = (const float*)d_in[5];
  const float* b3 = (const float*)d_in[6];
  const float* svec = (const float*)d_in[7];
  const int* src = (const int*)d_in[8];
  const int* dst = (const int*)d_in[9];

  const int DIN = 256, DH = 256, DOUT = 32, KHOP = 16;
  const int N = in_sizes[0] / DIN;
  const int E = in_sizes[8];
  const int nbuck = (N + (1 << BSHIFT) - 1) >> BSHIFT;

  char* w = (char*)d_ws;
  auto alloc = [&](size_t bytes) {
    char* p = w;
    w += (bytes + 255) & ~(size_t)255;
    return p;
  };
  ushort* featsb = (ushort*)alloc((size_t)N * DIN * 2);  // after gemm1: hs buffers 0..7
  ushort* x1b = (ushort*)alloc((size_t)N * DH * 2);      // after gemm23: hs buffers 8..15
  ushort* w1t = (ushort*)alloc((size_t)DIN * DH * 2);
  ushort* w2t = (ushort*)alloc((size_t)DH * DH * 2);
  ushort* w3t = (ushort*)alloc((size_t)DH * DOUT * 2);
  ushort* hs16 = (ushort*)alloc((size_t)N * DOUT * 2);
  float* nrm = (float*)alloc((size_t)N * 4);
  float* invdeg = (float*)alloc((size_t)N * 4);
  float* sdeg = (float*)alloc((size_t)N * 4);
  int* rp  = (int*)alloc((size_t)(N + 1) * 4);
  int* bhist = (int*)alloc((size_t)NBMAX * 4);
  int* bbase = (int*)alloc((size_t)(NBMAX + 1) * 4);
  int* gfill = (int*)alloc((size_t)NBMAX * 4);
  int* ss  = (int*)alloc((size_t)E * 4);
  int* tmp = (int*)alloc((size_t)E * 4);
  float* xout = (float*)d_out;

  const size_t seg = (size_t)N * DOUT;  // ushorts per hop buffer
  auto hsptr = [&](int k) -> ushort* {
    if (k < 8) return featsb + (size_t)k * seg;
    if (k < 16) return x1b + (size_t)(k - 8) * seg;
    return hs16;
  };

  // conversions
  k_f32_to_bf16<<<dim3((N * DIN / 4 + 255) / 256), 256, 0, stream>>>(feats, featsb, N * DIN / 4);
  k_convT<<<dim3((DIN * DH + 255) / 256), 256, 0, stream>>>(W1, w1t, DIN, DH);
  k_convT<<<dim3((DH * DH + 255) / 256), 256, 0, stream>>>(W2, w2t, DH, DH);
  k_convT<<<dim3((DH * DOUT + 255) / 256), 256, 0, stream>>>(W3, w3t, DH, DOUT);

  // graph prep
  (void)hipMemsetAsync(bhist, 0, (size_t)NBMAX * 4, stream);
  (void)hipMemsetAsync(gfill, 0, (size_t)NBMAX * 4, stream);
  int nchunk = (E + 4095) / 4096;
  k_bucket_hist<<<dim3(nchunk), 256, 0, stream>>>(dst, bhist, E);
  k_bucket_scan<<<dim3(1), 256, 0, stream>>>(bhist, bbase);
  k_bucket_scatter<<<dim3(nchunk), 256, 0, stream>>>(src, dst, bbase, gfill, tmp, E, nbuck);
  k_bucket_sort<<<dim3(nbuck), 256, 0, stream>>>(tmp, bbase, rp, nrm, invdeg, sdeg, ss, N, E);

  // MLP: GEMM1 then fused GEMM2+GEMM3+hop0-pool
  dim3 g1((N + 127) / 128, DH / 128);
  k_gemm1<<<g1, 256, 0, stream>>>(featsb, w1t, b1, x1b, N, DH);
  k_gemm23<<<dim3((N + 63) / 64), 256, 0, stream>>>(x1b, w2t, b2, w3t, b3, svec, nrm, xout,
                                                    hsptr(0), N);

  // 16 hops (one node per wave), then one pooling pass over hops 1..16
  for (int h = 0; h < KHOP; ++h) {
    k_prop<<<dim3((N + 3) / 4), 256, 0, stream>>>(hsptr(h), hsptr(h + 1), rp, ss, invdeg, N);
  }
  k_pool<<<dim3((N * 4 + 255) / 256), 256, 0, stream>>>(hsptr(0), hsptr(8), hs16, sdeg, svec,
                                                        xout, N);
}